// Round 3
// baseline (560.951 us; speedup 1.0000x reference)
//
#include <hip/hip_runtime.h>
#include <cmath>
#include <complex>

#define TPB 512
#define NPB 8            // nodes (one wave each) per block
#define EPG 16           // edges per chunk (MFMA M dimension)
#define NM 115
#define NW3J 363
#define SCAN_T 1024
#define NBUCK 256
#define W2N (352*64)     // repacked w2^T bf16 elements [n][k]

typedef __attribute__((ext_vector_type(8))) short bf16x8;
typedef __attribute__((ext_vector_type(4))) float f32x4;
typedef uint4 __attribute__((may_alias)) uint4a;   // TBAA-safe LDS access type

// ---------------- host-side W3J construction (exact port of reference) ------
namespace {

double fct(int n){ double r=1; for(int i=2;i<=n;i++) r*=i; return r; }

double su2_cg(int j1,int j2,int j3,int m1,int m2,int m3){
  if(m1+m2!=m3) return 0.0;
  double pref = std::sqrt((2*j3+1)*fct(j1+j2-j3)*fct(j1-j2+j3)*fct(-j1+j2+j3)/fct(j1+j2+j3+1));
  pref *= std::sqrt(fct(j3+m3)*fct(j3-m3)*fct(j1-m1)*fct(j1+m1)*fct(j2-m2)*fct(j2+m2));
  double s=0;
  for(int k=0;k<=j1+j2-j3;k++){
    int d0=k, d1=j1+j2-j3-k, d2=j1-m1-k, d3=j2+m2-k, d4=j3-j2+m1+k, d5=j3-j1-m2+k;
    if(d0<0||d1<0||d2<0||d3<0||d4<0||d5<0) continue;
    double t = 1.0/(fct(d0)*fct(d1)*fct(d2)*fct(d3)*fct(d4)*fct(d5));
    s += (k&1)? -t : t;
  }
  return pref*s;
}

typedef std::complex<double> cd;

void qmat(int l, cd q[5][5]){
  for(int i=0;i<5;i++) for(int j=0;j<5;j++) q[i][j] = cd(0,0);
  const double is2 = 1.0/std::sqrt(2.0);
  for(int m=-l;m<0;m++){ q[l+m][l-m] = cd(is2,0); q[l+m][l+m] = cd(0,-is2); }
  q[l][l] = cd(1,0);
  for(int m=1;m<=l;m++){ double sg = (m&1)? -1.0: 1.0; q[l+m][l+m] = cd(sg*is2,0); q[l+m][l-m] = cd(0, sg*is2); }
  cd ph(1,0), mi(0,-1);
  for(int t=0;t<l;t++) ph *= mi;
  for(int i=0;i<5;i++) for(int j=0;j<5;j++) q[i][j] *= ph;
}

void w3j_calc(int l1,int l2,int l3,double* out){
  int n1=2*l1+1,n2=2*l2+1,n3=2*l3+1;
  double C[5][5][5] = {};
  for(int m1=-l1;m1<=l1;m1++)for(int m2=-l2;m2<=l2;m2++)for(int m3=-l3;m3<=l3;m3++)
    C[l1+m1][l2+m2][l3+m3] = su2_cg(l1,l2,l3,m1,m2,m3);
  cd q1[5][5], q2[5][5], q3[5][5];
  qmat(l1,q1); qmat(l2,q2); qmat(l3,q3);
  double wr[125], wi[125];
  double nr=0, ni=0;
  for(int a=0;a<n1;a++)for(int b=0;b<n2;b++)for(int c=0;c<n3;c++){
    cd s(0,0);
    for(int i=0;i<n1;i++)for(int k=0;k<n2;k++)for(int m=0;m<n3;m++)
      s += q1[i][a]*q2[k][b]*std::conj(q3[m][c])*C[i][k][m];
    int idx = (a*n2+b)*n3+c;
    wr[idx]=s.real(); wi[idx]=s.imag();
    nr += s.real()*s.real(); ni += s.imag()*s.imag();
  }
  bool useR = std::sqrt(nr) >= std::sqrt(ni);
  double nn = std::sqrt(useR? nr: ni);
  for(int q=0;q<n1*n2*n3;q++) out[q] = (useR? wr[q]: wi[q])/nn;
}

struct UploadArg {
  float w3j[NW3J];        // PATH_W premultiplied, dense per path
  unsigned int meta[NM];  // per M-entry: woff | nc<<10 | nb<<14 | boff<<18
};

UploadArg g_upload;

struct BuildInit {
  BuildInit(){
    const int P[11][3] = {{0,0,0},{0,1,1},{0,2,2},{1,0,1},{1,1,0},{1,1,2},
                          {1,2,1},{2,0,2},{2,1,1},{2,2,0},{2,2,2}};
    const int cnt[3] = {3,4,4};
    const int AO[3] = {0,1,4};
    int off = 0, t = 0;
    for(int p=0;p<11;p++){
      int i=P[p][0], j=P[p][1], k=P[p][2];
      int na=2*i+1, nb=2*j+1, nc=2*k+1;
      double W[125];
      w3j_calc(i,j,k,W);
      double pw = std::sqrt((2.0*k+1.0)/(double)cnt[k]);
      for(int q=0;q<na*nb*nc;q++) g_upload.w3j[off+q] = (float)(W[q]*pw);
      for(int a=0;a<na;a++)
        for(int c=0;c<nc;c++)
          g_upload.meta[t++] = (unsigned)((off + a*nb*nc + c) | (nc<<10) | (nb<<14) | (AO[j]<<18));
      off += na*nb*nc;
    }
  }
};
BuildInit g_build_init;

} // namespace

// ---------------- aux kernels -----------------------------------------------

// fused: degree count + w2^T bf16 repack: w2t[n*64+k] = bf16(w2[k][n]), n = p*32+u
__global__ void count_repack_kernel(const int* __restrict__ dst, int* __restrict__ counts,
                                    const float* __restrict__ w2,
                                    unsigned short* __restrict__ w2t, int E){
  int i = blockIdx.x*blockDim.x + threadIdx.x;
  if(i < W2N){
    int n = i >> 6, k = i & 63;
    unsigned ub = __float_as_uint(w2[k*352 + n]);
    ub = (ub + 0x7fffu + ((ub>>16)&1u)) >> 16;   // RNE to bf16
    w2t[i] = (unsigned short)ub;
  }
  if(i < E) atomicAdd(&counts[dst[i]], 1);
}

// single block: exclusive scan of counts -> off/cursor, plus degree-histogram
__global__ __launch_bounds__(SCAN_T) void megascan_kernel(const int* __restrict__ counts,
                                                          int* __restrict__ off,
                                                          int* __restrict__ cursor,
                                                          int* __restrict__ bcur, int NN){
  __shared__ int part[SCAN_T];
  __shared__ int lh[NBUCK];
  int t = threadIdx.x;
  if(t < NBUCK) lh[t] = 0;
  __syncthreads();
  int C = (NN + SCAN_T - 1)/SCAN_T;
  int base = t*C;
  int lim = min(base+C, NN);
  int s = 0;
  for(int i=base;i<lim;i++){
    int c = counts[i];
    s += c;
    atomicAdd(&lh[min(c, NBUCK-1)], 1);
  }
  part[t] = s;
  __syncthreads();
  for(int d=1; d<SCAN_T; d<<=1){
    int v = (t>=d)? part[t-d] : 0;
    __syncthreads();
    part[t] += v;
    __syncthreads();
  }
  int run = part[t] - s;
  for(int i=base;i<lim;i++){ off[i]=run; cursor[i]=run; run += counts[i]; }
  if(t == SCAN_T-1) off[NN] = part[t];
  __syncthreads();
  if(t == 0){
    int r = 0;
    for(int b=0;b<NBUCK;b++){ bcur[b] = r; r += lh[b]; }
  }
}

// fused: node bucket-sort scatter + edge CSR scatter
__global__ void scatter_kernel(const int* __restrict__ dst, const int* __restrict__ counts,
                               int* __restrict__ cursor, int* __restrict__ bcur,
                               int* __restrict__ node_order, int* __restrict__ eid,
                               int NN, int E){
  int i = blockIdx.x*blockDim.x + threadIdx.x;
  if(i < NN){
    int p = atomicAdd(&bcur[min(counts[i], NBUCK-1)], 1);
    node_order[p] = i;
  }
  if(i < E){
    int p = atomicAdd(&cursor[dst[i]], 1);
    eid[p] = i;
  }
}

// ---------------- main node-owned kernel ------------------------------------
// One wave (64 lanes) per node. EPG=16 edges per chunk. MLP2 (h[16][64] @
// w2[64][352]) runs on MFMA 16x16x32 bf16 with hi/lo split of h for accuracy.
// A-fragments are built ENTIRELY IN REGISTERS: lane (q,le) computes exactly
// the h values its fragment needs (edge le, k = q*8+0..7 and 32+q*8+0..7).
// No LDS round-trip for the A-tile -> no cross-lane assembly hazard.
// B from swizzled LDS [n][k] (read-only after __syncthreads).
// MFMA C layout (verified): col = lane&15 (output col n), row = 4*(lane>>4)+reg
// (edge). Any HW k-permutation cancels since A and B use the same convention.

__global__ __launch_bounds__(TPB, 2) void node_kernel(
    const float* __restrict__ nodes,
    const float* __restrict__ pos,
    const int* __restrict__ src,
    const int* __restrict__ node_order,
    const int* __restrict__ off,
    const int* __restrict__ eid,
    const unsigned short* __restrict__ w2t,
    const float* __restrict__ w1,
    const float* __restrict__ b1,
    const float* __restrict__ b2,
    float* __restrict__ outp,
    int NN,
    UploadArg up)
{
  __shared__ __align__(16) unsigned short s_w2t[W2N];        // 44 KB, swizzled [n][k]
  __shared__ float s_w1[512];
  __shared__ float s_b1[64];
  __shared__ float s_b2[352];
  __shared__ float s_w3j[NW3J];
  __shared__ unsigned int s_meta[NM];
  __shared__ float s_M[NPB][16][117];                          // [wave][edge][M-entry]
  __shared__ float s_y[NPB][16][12];
  __shared__ float s_cut[NPB][16];
  __shared__ int   s_srcv[NPB][16];

  const int tid = threadIdx.x;

  // one-time staging
  for(int t=tid; t<NW3J; t+=TPB) s_w3j[t] = up.w3j[t];
  for(int t=tid; t<NM;   t+=TPB) s_meta[t] = up.meta[t];
  for(int t=tid; t<512;  t+=TPB) s_w1[t]  = w1[t];
  if(tid < 64) s_b1[tid] = b1[tid];
  if(tid >= 64 && tid < 64+352) s_b2[tid-64] = b2[tid-64];
  {
    const uint4* g4 = (const uint4*)w2t;
    uint4a* s4 = (uint4a*)s_w2t;
    for(int c=tid; c<W2N/8; c+=TPB) s4[c ^ ((c>>3)&7)] = g4[c];  // byte ^= ((n&7)<<4)
  }
  __syncthreads();   // ONLY barrier. Waves independent afterwards.

  const int lane = tid & 63;
  const int wv   = tid >> 6;
  const int q    = lane >> 4;    // quarter: A/B k-group; C row-group
  const int le   = lane & 15;    // edge (A row) / output col (C col)
  const int swz  = (le & 7) << 4;

  const int nidx = blockIdx.x*NPB + wv;
  const bool active = nidx < NN;
  const int node = active ? node_order[nidx] : 0;
  const int start = off[node];
  const int deg = active ? (off[node+1] - start) : 0;

  const float dpx = pos[node*3+0], dpy = pos[node*3+1], dpz = pos[node*3+2];

  constexpr int PI_[11]   = {0,0,0,1,1,1,1,2,2,2,2};
  constexpr int PK_[11]   = {0,1,2,1,0,2,1,2,1,0,2};
  constexpr int TOFF_[11] = {0,1,4,9,18,21,36,45,70,85,90};
  constexpr int AO_[3]    = {0,1,4};

  float accv[2][9];
  #pragma unroll
  for(int uh=0; uh<2; uh++)
    #pragma unroll
    for(int m=0; m<9; m++) accv[uh][m] = 0.0f;

  const char* wtb = (const char*)s_w2t;
  const int nch = (deg + EPG - 1)/EPG;

  for(int ch=0; ch<nch; ch++){
    // ---- geometry for edge le (4x redundant across quarters; keeps bessel in-lane)
    const int ei = ch*EPG + le;
    const bool valid = ei < deg;
    const int eg = valid ? eid[start + ei] : 0;
    const int se = valid ? src[eg] : node;      // invalid -> self: d=0, bessel masked
    const float px = pos[se*3+0]-dpx, py = pos[se*3+1]-dpy, pz = pos[se*3+2]-dpz;
    const float d2 = px*px + py*py + pz*pz;
    const float d  = sqrtf(d2);
    const float inv = 1.0f / fmaxf(d, 1e-12f);
    const float x = px*inv, y = py*inv, z = pz*inv;

    float bes[8];
    {
      float tt = d * 0.2f;
      float st = (tt > 0.0f) ? tt : 1.0f;
      float msk = (tt > 0.0f && tt < 1.0f) ? 1.0f : 0.0f;
      float ang = 3.14159265358979323846f * tt;
      float s1 = __sinf(ang), c1 = __cosf(ang);
      float kk = 0.6324555320336759f * msk / st;
      float c2 = 2.0f*c1, sp = 0.0f, sc = s1;
      bes[0] = kk*s1;
      #pragma unroll
      for(int n=1;n<8;n++){ float sn = c2*sc - sp; sp = sc; sc = sn; bes[n] = kk*sn; }
    }
    if(q == 0){
      float yv[9];
      yv[0] = 1.0f;
      yv[1] = 1.7320508075688772f*y;
      yv[2] = 1.7320508075688772f*z;
      yv[3] = 1.7320508075688772f*x;
      yv[4] = 3.872983346207417f*x*y;
      yv[5] = 3.872983346207417f*y*z;
      yv[6] = 1.118033988749895f*(3.0f*z*z - 1.0f);
      yv[7] = 3.872983346207417f*x*z;
      yv[8] = 1.9364916731037085f*(x*x - y*y);
      #pragma unroll
      for(int m=0;m<9;m++) s_y[wv][le][m] = yv[m];
      float uu = d*0.25f, u2 = uu*uu, u5 = u2*u2*uu;
      float env = 1.0f - 6.0f*u5 + 5.0f*u5*uu;
      s_cut[wv][le] = (valid && d < 4.0f) ? env : 0.0f;   // padding edges gated here
      s_srcv[wv][le] = se;
    }

    // ---- MLP1, in-register A fragments: lane needs h[edge le][k] for
    //      k = q*8+e (Ah0/Al0) and k = 32+q*8+e (Ah1/Al1), e = 0..7.
    bf16x8 Ah0, Al0, Ah1, Al1;
    #pragma unroll
    for(int e=0; e<8; e++){
      #pragma unroll
      for(int half=0; half<2; half++){
        const int j = half*32 + q*8 + e;
        float a = s_b1[j];
        #pragma unroll
        for(int k=0;k<8;k++) a += bes[k]*s_w1[k*64+j];
        float sg = 1.0f/(1.0f + __expf(-a));
        float h = a*sg;
        unsigned ub = __float_as_uint(h);
        unsigned hb = (ub + 0x7fffu + ((ub>>16)&1u)) >> 16;      // RNE to bf16
        float hif = __uint_as_float(hb << 16);
        unsigned ul = __float_as_uint(h - hif);
        unsigned lb = (ul + 0x7fffu + ((ul>>16)&1u)) >> 16;      // residual to bf16
        if(half == 0){ Ah0[e] = (short)hb; Al0[e] = (short)lb; }
        else         { Ah1[e] = (short)hb; Al1[e] = (short)lb; }
      }
    }

    // ---- M[a,c] = sum_b W3J[a,b,c]*y[b], per edge le, entries t = q,q+4,...
    for(int t=q; t<NM; t+=4){
      const unsigned md = s_meta[t];
      const int woff = md & 1023;
      const int nc2  = (md>>10) & 15;
      const int nb   = (md>>14) & 15;
      const int boff = (md>>18) & 15;
      float s = 0.0f;
      for(int b=0;b<nb;b++) s += s_w3j[woff + b*nc2] * s_y[wv][le][boff + b];
      s_M[wv][le][t] = s;
    }
    asm volatile("" ::: "memory");   // order cross-lane LDS stores before reads

    float cut4[4]; int se4[4];
    #pragma unroll
    for(int i=0;i<4;i++){ cut4[i] = s_cut[wv][4*q+i]; se4[i] = s_srcv[wv][4*q+i]; }

    // ---- per u-half: gather x, then 11 paths: MFMA radial tile + tensor product
    #pragma unroll
    for(int uh=0; uh<2; uh++){
      const int u = uh*16 + le;
      float xv[4][9];
      #pragma unroll
      for(int i=0;i<4;i++){
        const float* nr = nodes + (long)se4[i]*288;
        xv[i][0] = nr[u];
        #pragma unroll
        for(int c=0;c<3;c++) xv[i][1+c] = nr[32 + u*3 + c];
        #pragma unroll
        for(int c=0;c<5;c++) xv[i][4+c] = nr[128 + u*5 + c];
      }
      #pragma unroll
      for(int p=0;p<11;p++){
        const int t2 = 2*p + uh;                       // 16-col tile: cols p*32+uh*16+[0,16)
        const int bb = (t2*2048 + le*128 + q*16) ^ swz;
        const bf16x8 B0 = __builtin_bit_cast(bf16x8, *(const uint4a*)(wtb + bb));
        const bf16x8 B1 = __builtin_bit_cast(bf16x8, *(const uint4a*)(wtb + (bb^64)));
        f32x4 acc = {0.0f, 0.0f, 0.0f, 0.0f};
        acc = __builtin_amdgcn_mfma_f32_16x16x32_bf16(Ah0, B0, acc, 0, 0, 0);
        acc = __builtin_amdgcn_mfma_f32_16x16x32_bf16(Al0, B0, acc, 0, 0, 0);
        acc = __builtin_amdgcn_mfma_f32_16x16x32_bf16(Ah1, B1, acc, 0, 0, 0);
        acc = __builtin_amdgcn_mfma_f32_16x16x32_bf16(Al1, B1, acc, 0, 0, 0);
        const float bv = s_b2[p*32 + u];
        const int na  = 2*PI_[p] + 1;
        const int ncc = 2*PK_[p] + 1;
        #pragma unroll
        for(int i=0;i<4;i++){                          // edge = 4*q + i  (C row)
          const float wr = (acc[i] + bv) * cut4[i];    // cut=0 kills padding edges
          const float* Me = &s_M[wv][4*q + i][0];
          #pragma unroll
          for(int a=0;a<na;a++){
            const float xw = xv[i][AO_[PI_[p]] + a] * wr;
            #pragma unroll
            for(int c=0;c<ncc;c++)
              accv[uh][AO_[PK_[p]] + c] += xw * Me[TOFF_[p] + a*ncc + c];
          }
        }
      }
    }
    asm volatile("" ::: "memory");   // order this chunk's reads before next chunk's stores
  } // chunks

  // ---- reduce partial sums across the 4 quarters, write output
  #pragma unroll
  for(int uh=0; uh<2; uh++)
    #pragma unroll
    for(int m=0; m<9; m++){
      float v = accv[uh][m];
      v += __shfl_xor(v, 16);
      v += __shfl_xor(v, 32);
      accv[uh][m] = v;
    }
  if(active && lane < 16){
    float* ob = outp + (long)node*288;
    #pragma unroll
    for(int uh=0; uh<2; uh++){
      const int u = uh*16 + lane;
      ob[u] = 0.2f*accv[uh][0];
      #pragma unroll
      for(int c=0;c<3;c++) ob[32 + u*3 + c] = 0.2f*accv[uh][1+c];
      #pragma unroll
      for(int c=0;c<5;c++) ob[128 + u*5 + c] = 0.2f*accv[uh][4+c];
    }
  }
}

// ---------------- launch ----------------------------------------------------

extern "C" void kernel_launch(void* const* d_in, const int* in_sizes, int n_in,
                              void* d_out, int out_size, void* d_ws, size_t ws_size,
                              hipStream_t stream) {
  const float* nodes = (const float*)d_in[0];
  const float* pos   = (const float*)d_in[1];
  const int* src = (const int*)d_in[2];
  const int* dst = (const int*)d_in[3];
  const float* w1 = (const float*)d_in[4];
  const float* b1 = (const float*)d_in[5];
  const float* w2 = (const float*)d_in[6];
  const float* b2 = (const float*)d_in[7];

  const int E  = in_sizes[2];
  const int NN = in_sizes[0] / 288;
  float* outp = (float*)d_out;

  // workspace layout: w2t first (16B-aligned), then ints
  unsigned short* w2t = (unsigned short*)d_ws;       // W2N bf16 (44 KB)
  int* counts     = (int*)(w2t + W2N);               // NN (zeroed)
  int* offp       = counts + NN;                     // NN+1
  int* cursor     = offp + NN + 1;                   // NN
  int* bcur       = cursor + NN;                     // NBUCK
  int* node_order = bcur + NBUCK;                    // NN
  int* eid        = node_order + NN;                 // E

  hipMemsetAsync(counts, 0, (size_t)NN*sizeof(int), stream);

  int g1 = (max(E, W2N) + 255)/256;
  count_repack_kernel<<<g1, 256, 0, stream>>>(dst, counts, w2, w2t, E);
  megascan_kernel<<<1, SCAN_T, 0, stream>>>(counts, offp, cursor, bcur, NN);
  int g2 = (max(E, NN) + 255)/256;
  scatter_kernel<<<g2, 256, 0, stream>>>(dst, counts, cursor, bcur, node_order, eid, NN, E);

  int nblocks = (NN + NPB - 1)/NPB;
  node_kernel<<<nblocks, TPB, 0, stream>>>(nodes, pos, src, node_order, offp, eid,
                                           w2t, w1, b1, b2, outp, NN, g_upload);
}

// Round 4
// 559.237 us; speedup vs baseline: 1.0031x; 1.0031x over previous
//
#include <hip/hip_runtime.h>
#include <cmath>
#include <complex>

#define TPB 512
#define NPB 8            // nodes (one wave each) per block
#define EPG 16           // edges per chunk (MFMA M dimension)
#define NM 115
#define NW3J 363
#define SCAN_T 1024
#define NBUCK 256
#define W2N (352*64)     // repacked w2^T bf16 elements [n][k]

typedef __attribute__((ext_vector_type(8))) short bf16x8;
typedef __attribute__((ext_vector_type(4))) float f32x4;
typedef uint4 __attribute__((may_alias)) uint4a;   // TBAA-safe LDS access type

// ---------------- host-side W3J construction (exact port of reference) ------
namespace {

double fct(int n){ double r=1; for(int i=2;i<=n;i++) r*=i; return r; }

double su2_cg(int j1,int j2,int j3,int m1,int m2,int m3){
  if(m1+m2!=m3) return 0.0;
  double pref = std::sqrt((2*j3+1)*fct(j1+j2-j3)*fct(j1-j2+j3)*fct(-j1+j2+j3)/fct(j1+j2+j3+1));
  pref *= std::sqrt(fct(j3+m3)*fct(j3-m3)*fct(j1-m1)*fct(j1+m1)*fct(j2-m2)*fct(j2+m2));
  double s=0;
  for(int k=0;k<=j1+j2-j3;k++){
    int d0=k, d1=j1+j2-j3-k, d2=j1-m1-k, d3=j2+m2-k, d4=j3-j2+m1+k, d5=j3-j1-m2+k;
    if(d0<0||d1<0||d2<0||d3<0||d4<0||d5<0) continue;
    double t = 1.0/(fct(d0)*fct(d1)*fct(d2)*fct(d3)*fct(d4)*fct(d5));
    s += (k&1)? -t : t;
  }
  return pref*s;
}

typedef std::complex<double> cd;

void qmat(int l, cd q[5][5]){
  for(int i=0;i<5;i++) for(int j=0;j<5;j++) q[i][j] = cd(0,0);
  const double is2 = 1.0/std::sqrt(2.0);
  for(int m=-l;m<0;m++){ q[l+m][l-m] = cd(is2,0); q[l+m][l+m] = cd(0,-is2); }
  q[l][l] = cd(1,0);
  for(int m=1;m<=l;m++){ double sg = (m&1)? -1.0: 1.0; q[l+m][l+m] = cd(sg*is2,0); q[l+m][l-m] = cd(0, sg*is2); }
  cd ph(1,0), mi(0,-1);
  for(int t=0;t<l;t++) ph *= mi;
  for(int i=0;i<5;i++) for(int j=0;j<5;j++) q[i][j] *= ph;
}

void w3j_calc(int l1,int l2,int l3,double* out){
  int n1=2*l1+1,n2=2*l2+1,n3=2*l3+1;
  double C[5][5][5] = {};
  for(int m1=-l1;m1<=l1;m1++)for(int m2=-l2;m2<=l2;m2++)for(int m3=-l3;m3<=l3;m3++)
    C[l1+m1][l2+m2][l3+m3] = su2_cg(l1,l2,l3,m1,m2,m3);
  cd q1[5][5], q2[5][5], q3[5][5];
  qmat(l1,q1); qmat(l2,q2); qmat(l3,q3);
  double wr[125], wi[125];
  double nr=0, ni=0;
  for(int a=0;a<n1;a++)for(int b=0;b<n2;b++)for(int c=0;c<n3;c++){
    cd s(0,0);
    for(int i=0;i<n1;i++)for(int k=0;k<n2;k++)for(int m=0;m<n3;m++)
      s += q1[i][a]*q2[k][b]*std::conj(q3[m][c])*C[i][k][m];
    int idx = (a*n2+b)*n3+c;
    wr[idx]=s.real(); wi[idx]=s.imag();
    nr += s.real()*s.real(); ni += s.imag()*s.imag();
  }
  bool useR = std::sqrt(nr) >= std::sqrt(ni);
  double nn = std::sqrt(useR? nr: ni);
  for(int q=0;q<n1*n2*n3;q++) out[q] = (useR? wr[q]: wi[q])/nn;
}

struct UploadArg {
  float w3j[NW3J];        // PATH_W premultiplied, dense per path
  unsigned int meta[NM];  // per M-entry: woff | nc<<10 | nb<<14 | boff<<18
};

UploadArg g_upload;

struct BuildInit {
  BuildInit(){
    const int P[11][3] = {{0,0,0},{0,1,1},{0,2,2},{1,0,1},{1,1,0},{1,1,2},
                          {1,2,1},{2,0,2},{2,1,1},{2,2,0},{2,2,2}};
    const int cnt[3] = {3,4,4};
    const int AO[3] = {0,1,4};
    int off = 0, t = 0;
    for(int p=0;p<11;p++){
      int i=P[p][0], j=P[p][1], k=P[p][2];
      int na=2*i+1, nb=2*j+1, nc=2*k+1;
      double W[125];
      w3j_calc(i,j,k,W);
      double pw = std::sqrt((2.0*k+1.0)/(double)cnt[k]);
      for(int q=0;q<na*nb*nc;q++) g_upload.w3j[off+q] = (float)(W[q]*pw);
      for(int a=0;a<na;a++)
        for(int c=0;c<nc;c++)
          g_upload.meta[t++] = (unsigned)((off + a*nb*nc + c) | (nc<<10) | (nb<<14) | (AO[j]<<18));
      off += na*nb*nc;
    }
  }
};
BuildInit g_build_init;

} // namespace

// ---------------- aux kernels -----------------------------------------------

// fused: degree count + w2^T bf16 repack: w2t[n*64+k] = bf16(w2[k][n]), n = p*32+u
__global__ void count_repack_kernel(const int* __restrict__ dst, int* __restrict__ counts,
                                    const float* __restrict__ w2,
                                    unsigned short* __restrict__ w2t, int E){
  int i = blockIdx.x*blockDim.x + threadIdx.x;
  if(i < W2N){
    int n = i >> 6, k = i & 63;
    unsigned ub = __float_as_uint(w2[k*352 + n]);
    ub = (ub + 0x7fffu + ((ub>>16)&1u)) >> 16;   // RNE to bf16
    w2t[i] = (unsigned short)ub;
  }
  if(i < E) atomicAdd(&counts[dst[i]], 1);
}

// single block: exclusive scan of counts -> off/cursor, plus degree-histogram
__global__ __launch_bounds__(SCAN_T) void megascan_kernel(const int* __restrict__ counts,
                                                          int* __restrict__ off,
                                                          int* __restrict__ cursor,
                                                          int* __restrict__ bcur, int NN){
  __shared__ int part[SCAN_T];
  __shared__ int lh[NBUCK];
  int t = threadIdx.x;
  if(t < NBUCK) lh[t] = 0;
  __syncthreads();
  int C = (NN + SCAN_T - 1)/SCAN_T;
  int base = t*C;
  int lim = min(base+C, NN);
  int s = 0;
  for(int i=base;i<lim;i++){
    int c = counts[i];
    s += c;
    atomicAdd(&lh[min(c, NBUCK-1)], 1);
  }
  part[t] = s;
  __syncthreads();
  for(int d=1; d<SCAN_T; d<<=1){
    int v = (t>=d)? part[t-d] : 0;
    __syncthreads();
    part[t] += v;
    __syncthreads();
  }
  int run = part[t] - s;
  for(int i=base;i<lim;i++){ off[i]=run; cursor[i]=run; run += counts[i]; }
  if(t == SCAN_T-1) off[NN] = part[t];
  __syncthreads();
  if(t == 0){
    int r = 0;
    for(int b=0;b<NBUCK;b++){ bcur[b] = r; r += lh[b]; }
  }
}

// fused: node bucket-sort scatter + edge CSR scatter
__global__ void scatter_kernel(const int* __restrict__ dst, const int* __restrict__ counts,
                               int* __restrict__ cursor, int* __restrict__ bcur,
                               int* __restrict__ node_order, int* __restrict__ eid,
                               int NN, int E){
  int i = blockIdx.x*blockDim.x + threadIdx.x;
  if(i < NN){
    int p = atomicAdd(&bcur[min(counts[i], NBUCK-1)], 1);
    node_order[p] = i;
  }
  if(i < E){
    int p = atomicAdd(&cursor[dst[i]], 1);
    eid[p] = i;
  }
}

// ---------------- main node-owned kernel ------------------------------------
// One wave (64 lanes) per node. EPG=16 edges per chunk. MLP2 (h[16][64] @
// w2[64][352]) runs on MFMA 16x16x32 bf16 with hi/lo split of h for accuracy.
// A-fragments built entirely in registers (round-3 correctness fix).
// OCCUPANCY/REGALLOC NOTE: LDS=117.8KB caps the CU at 1 block = 2 waves/EU.
// Without a waves-per-eu MAX, the allocator targeted 4 waves/EU (128 VGPR)
// and spilled ~100 dwords/lane/chunk -> 420MB scratch writes + L2 thrash
// (round-3 counters). amdgpu_waves_per_eu(2,2) pins the budget at 256 VGPR,
// which costs nothing (LDS-capped anyway) and eliminates the spill.

__attribute__((amdgpu_waves_per_eu(2, 2)))
__global__ void __launch_bounds__(TPB) node_kernel(
    const float* __restrict__ nodes,
    const float* __restrict__ pos,
    const int* __restrict__ src,
    const int* __restrict__ node_order,
    const int* __restrict__ off,
    const int* __restrict__ eid,
    const unsigned short* __restrict__ w2t,
    const float* __restrict__ w1,
    const float* __restrict__ b1,
    const float* __restrict__ b2,
    float* __restrict__ outp,
    int NN,
    UploadArg up)
{
  __shared__ __align__(16) unsigned short s_w2t[W2N];        // 44 KB, swizzled [n][k]
  __shared__ float s_w1[512];
  __shared__ float s_b1[64];
  __shared__ float s_b2[352];
  __shared__ float s_w3j[NW3J];
  __shared__ unsigned int s_meta[NM];
  __shared__ float s_M[NPB][16][117];                          // [wave][edge][M-entry]
  __shared__ float s_y[NPB][16][12];
  __shared__ float s_cut[NPB][16];
  __shared__ int   s_srcv[NPB][16];

  const int tid = threadIdx.x;

  // one-time staging
  for(int t=tid; t<NW3J; t+=TPB) s_w3j[t] = up.w3j[t];
  for(int t=tid; t<NM;   t+=TPB) s_meta[t] = up.meta[t];
  for(int t=tid; t<512;  t+=TPB) s_w1[t]  = w1[t];
  if(tid < 64) s_b1[tid] = b1[tid];
  if(tid >= 64 && tid < 64+352) s_b2[tid-64] = b2[tid-64];
  {
    const uint4* g4 = (const uint4*)w2t;
    uint4a* s4 = (uint4a*)s_w2t;
    for(int c=tid; c<W2N/8; c+=TPB) s4[c ^ ((c>>3)&7)] = g4[c];  // byte ^= ((n&7)<<4)
  }
  __syncthreads();   // ONLY barrier. Waves independent afterwards.

  const int lane = tid & 63;
  const int wv   = tid >> 6;
  const int q    = lane >> 4;    // quarter: A/B k-group; C row-group
  const int le   = lane & 15;    // edge (A row) / output col (C col)
  const int swz  = (le & 7) << 4;

  const int nidx = blockIdx.x*NPB + wv;
  const bool active = nidx < NN;
  const int node = active ? node_order[nidx] : 0;
  const int start = off[node];
  const int deg = active ? (off[node+1] - start) : 0;

  const float dpx = pos[node*3+0], dpy = pos[node*3+1], dpz = pos[node*3+2];

  constexpr int PI_[11]   = {0,0,0,1,1,1,1,2,2,2,2};
  constexpr int PK_[11]   = {0,1,2,1,0,2,1,2,1,0,2};
  constexpr int TOFF_[11] = {0,1,4,9,18,21,36,45,70,85,90};
  constexpr int AO_[3]    = {0,1,4};

  float accv[2][9];
  #pragma unroll
  for(int uh=0; uh<2; uh++)
    #pragma unroll
    for(int m=0; m<9; m++) accv[uh][m] = 0.0f;

  const char* wtb = (const char*)s_w2t;
  const int nch = (deg + EPG - 1)/EPG;

  for(int ch=0; ch<nch; ch++){
    // ---- geometry for edge le (4x redundant across quarters; keeps bessel in-lane)
    const int ei = ch*EPG + le;
    const bool valid = ei < deg;
    const int eg = valid ? eid[start + ei] : 0;
    const int se = valid ? src[eg] : node;      // invalid -> self: d=0, bessel masked
    const float px = pos[se*3+0]-dpx, py = pos[se*3+1]-dpy, pz = pos[se*3+2]-dpz;
    const float d2 = px*px + py*py + pz*pz;
    const float d  = sqrtf(d2);
    const float inv = 1.0f / fmaxf(d, 1e-12f);
    const float x = px*inv, y = py*inv, z = pz*inv;

    float bes[8];
    {
      float tt = d * 0.2f;
      float st = (tt > 0.0f) ? tt : 1.0f;
      float msk = (tt > 0.0f && tt < 1.0f) ? 1.0f : 0.0f;
      float ang = 3.14159265358979323846f * tt;
      float s1 = __sinf(ang), c1 = __cosf(ang);
      float kk = 0.6324555320336759f * msk / st;
      float c2 = 2.0f*c1, sp = 0.0f, sc = s1;
      bes[0] = kk*s1;
      #pragma unroll
      for(int n=1;n<8;n++){ float sn = c2*sc - sp; sp = sc; sc = sn; bes[n] = kk*sn; }
    }
    if(q == 0){
      float yv[9];
      yv[0] = 1.0f;
      yv[1] = 1.7320508075688772f*y;
      yv[2] = 1.7320508075688772f*z;
      yv[3] = 1.7320508075688772f*x;
      yv[4] = 3.872983346207417f*x*y;
      yv[5] = 3.872983346207417f*y*z;
      yv[6] = 1.118033988749895f*(3.0f*z*z - 1.0f);
      yv[7] = 3.872983346207417f*x*z;
      yv[8] = 1.9364916731037085f*(x*x - y*y);
      #pragma unroll
      for(int m=0;m<9;m++) s_y[wv][le][m] = yv[m];
      float uu = d*0.25f, u2 = uu*uu, u5 = u2*u2*uu;
      float env = 1.0f - 6.0f*u5 + 5.0f*u5*uu;
      s_cut[wv][le] = (valid && d < 4.0f) ? env : 0.0f;   // padding edges gated here
      s_srcv[wv][le] = se;
    }

    // ---- MLP1, in-register A fragments: lane needs h[edge le][k] for
    //      k = q*8+e (Ah0/Al0) and k = 32+q*8+e (Ah1/Al1), e = 0..7.
    bf16x8 Ah0, Al0, Ah1, Al1;
    #pragma unroll
    for(int e=0; e<8; e++){
      #pragma unroll
      for(int half=0; half<2; half++){
        const int j = half*32 + q*8 + e;
        float a = s_b1[j];
        #pragma unroll
        for(int k=0;k<8;k++) a += bes[k]*s_w1[k*64+j];
        float sg = 1.0f/(1.0f + __expf(-a));
        float h = a*sg;
        unsigned ub = __float_as_uint(h);
        unsigned hb = (ub + 0x7fffu + ((ub>>16)&1u)) >> 16;      // RNE to bf16
        float hif = __uint_as_float(hb << 16);
        unsigned ul = __float_as_uint(h - hif);
        unsigned lb = (ul + 0x7fffu + ((ul>>16)&1u)) >> 16;      // residual to bf16
        if(half == 0){ Ah0[e] = (short)hb; Al0[e] = (short)lb; }
        else         { Ah1[e] = (short)hb; Al1[e] = (short)lb; }
      }
    }

    // ---- M[a,c] = sum_b W3J[a,b,c]*y[b], per edge le, entries t = q,q+4,...
    for(int t=q; t<NM; t+=4){
      const unsigned md = s_meta[t];
      const int woff = md & 1023;
      const int nc2  = (md>>10) & 15;
      const int nb   = (md>>14) & 15;
      const int boff = (md>>18) & 15;
      float s = 0.0f;
      for(int b=0;b<nb;b++) s += s_w3j[woff + b*nc2] * s_y[wv][le][boff + b];
      s_M[wv][le][t] = s;
    }
    asm volatile("" ::: "memory");   // order cross-lane LDS stores before reads

    float cut4[4]; int se4[4];
    #pragma unroll
    for(int i=0;i<4;i++){ cut4[i] = s_cut[wv][4*q+i]; se4[i] = s_srcv[wv][4*q+i]; }

    // ---- per u-half: gather x, then 11 paths: MFMA radial tile + tensor product
    #pragma unroll
    for(int uh=0; uh<2; uh++){
      const int u = uh*16 + le;
      float xv[4][9];
      #pragma unroll
      for(int i=0;i<4;i++){
        const float* nr = nodes + (long)se4[i]*288;
        xv[i][0] = nr[u];
        #pragma unroll
        for(int c=0;c<3;c++) xv[i][1+c] = nr[32 + u*3 + c];
        #pragma unroll
        for(int c=0;c<5;c++) xv[i][4+c] = nr[128 + u*5 + c];
      }
      #pragma unroll
      for(int p=0;p<11;p++){
        const int t2 = 2*p + uh;                       // 16-col tile: cols p*32+uh*16+[0,16)
        const int bb = (t2*2048 + le*128 + q*16) ^ swz;
        const bf16x8 B0 = __builtin_bit_cast(bf16x8, *(const uint4a*)(wtb + bb));
        const bf16x8 B1 = __builtin_bit_cast(bf16x8, *(const uint4a*)(wtb + (bb^64)));
        f32x4 acc = {0.0f, 0.0f, 0.0f, 0.0f};
        acc = __builtin_amdgcn_mfma_f32_16x16x32_bf16(Ah0, B0, acc, 0, 0, 0);
        acc = __builtin_amdgcn_mfma_f32_16x16x32_bf16(Al0, B0, acc, 0, 0, 0);
        acc = __builtin_amdgcn_mfma_f32_16x16x32_bf16(Ah1, B1, acc, 0, 0, 0);
        acc = __builtin_amdgcn_mfma_f32_16x16x32_bf16(Al1, B1, acc, 0, 0, 0);
        const float bv = s_b2[p*32 + u];
        const int na  = 2*PI_[p] + 1;
        const int ncc = 2*PK_[p] + 1;
        #pragma unroll
        for(int i=0;i<4;i++){                          // edge = 4*q + i  (C row)
          const float wr = (acc[i] + bv) * cut4[i];    // cut=0 kills padding edges
          const float* Me = &s_M[wv][4*q + i][0];
          #pragma unroll
          for(int a=0;a<na;a++){
            const float xw = xv[i][AO_[PI_[p]] + a] * wr;
            #pragma unroll
            for(int c=0;c<ncc;c++)
              accv[uh][AO_[PK_[p]] + c] += xw * Me[TOFF_[p] + a*ncc + c];
          }
        }
      }
    }
    asm volatile("" ::: "memory");   // order this chunk's reads before next chunk's stores
  } // chunks

  // ---- reduce partial sums across the 4 quarters, write output
  #pragma unroll
  for(int uh=0; uh<2; uh++)
    #pragma unroll
    for(int m=0; m<9; m++){
      float v = accv[uh][m];
      v += __shfl_xor(v, 16);
      v += __shfl_xor(v, 32);
      accv[uh][m] = v;
    }
  if(active && lane < 16){
    float* ob = outp + (long)node*288;
    #pragma unroll
    for(int uh=0; uh<2; uh++){
      const int u = uh*16 + lane;
      ob[u] = 0.2f*accv[uh][0];
      #pragma unroll
      for(int c=0;c<3;c++) ob[32 + u*3 + c] = 0.2f*accv[uh][1+c];
      #pragma unroll
      for(int c=0;c<5;c++) ob[128 + u*5 + c] = 0.2f*accv[uh][4+c];
    }
  }
}

// ---------------- launch ----------------------------------------------------

extern "C" void kernel_launch(void* const* d_in, const int* in_sizes, int n_in,
                              void* d_out, int out_size, void* d_ws, size_t ws_size,
                              hipStream_t stream) {
  const float* nodes = (const float*)d_in[0];
  const float* pos   = (const float*)d_in[1];
  const int* src = (const int*)d_in[2];
  const int* dst = (const int*)d_in[3];
  const float* w1 = (const float*)d_in[4];
  const float* b1 = (const float*)d_in[5];
  const float* w2 = (const float*)d_in[6];
  const float* b2 = (const float*)d_in[7];

  const int E  = in_sizes[2];
  const int NN = in_sizes[0] / 288;
  float* outp = (float*)d_out;

  // workspace layout: w2t first (16B-aligned), then ints
  unsigned short* w2t = (unsigned short*)d_ws;       // W2N bf16 (44 KB)
  int* counts     = (int*)(w2t + W2N);               // NN (zeroed)
  int* offp       = counts + NN;                     // NN+1
  int* cursor     = offp + NN + 1;                   // NN
  int* bcur       = cursor + NN;                     // NBUCK
  int* node_order = bcur + NBUCK;                    // NN
  int* eid        = node_order + NN;                 // E

  hipMemsetAsync(counts, 0, (size_t)NN*sizeof(int), stream);

  int g1 = (max(E, W2N) + 255)/256;
  count_repack_kernel<<<g1, 256, 0, stream>>>(dst, counts, w2, w2t, E);
  megascan_kernel<<<1, SCAN_T, 0, stream>>>(counts, offp, cursor, bcur, NN);
  int g2 = (max(E, NN) + 255)/256;
  scatter_kernel<<<g2, 256, 0, stream>>>(dst, counts, cursor, bcur, node_order, eid, NN, E);

  int nblocks = (NN + NPB - 1)/NPB;
  node_kernel<<<nblocks, TPB, 0, stream>>>(nodes, pos, src, node_order, offp, eid,
                                           w2t, w1, b1, b2, outp, NN, g_upload);
}